// Round 4
// baseline (274.277 us; speedup 1.0000x reference)
//
#include <hip/hip_runtime.h>

// ---------------------------------------------------------------------------
// ActorCritic fused loss, MI355X.  T=8192, B=4096.
// Single-pass decoupled-lookback design (3 kernels):
//   k_init  : clear publish-flags + mask dtype probe (int32 {0,1} vs bool).
//   k_fused : per (chunk c, column-slice s) tile:
//             phase1: rewards -> chunk-local discounted sum S, publish.
//             walk  : deterministic two-level aggregate walk -> carry X.
//             phase2: re-read rewards (L2-warm) + v/lp/ent/mask -> 10 sums.
//   k_final : closed-form critic/actor losses.
// Block bid 0 handles the LAST chunk; all waits target lower blockIdx only
// (deadlock-free under in-order dispatch — rocPRIM lookback assumption).
// Walk order is fixed (no inclusive-shortcut) => bitwise replay-deterministic.
// ---------------------------------------------------------------------------

constexpr int T    = 8192;
constexpr int B    = 4096;
constexpr int B4   = B / 4;           // 1024 float4 columns
constexpr int BLK  = 256;
constexpr int WAVES = BLK / 64;
constexpr int L    = 32;              // chunk length
constexpr int NC   = T / L;           // 256 chunks
constexpr int SL   = 4;               // column slices (256 float4-cols each)
constexpr int NTILE = NC * SL;        // 1024 tiles = grid size
constexpr int GSZ  = 16;              // chunks per group
constexpr int NGRP = NC / GSZ;        // 16 groups

constexpr float GAMMA_F = 0.99f;
constexpr double cpow(double g, int n) { double r = 1.0; for (int i = 0; i < n; ++i) r *= g; return r; }
constexpr float G32  = (float)cpow(0.99, L);        // gamma^32
constexpr float G512 = (float)cpow(0.99, L * GSZ);  // gamma^512

// --------------------------------------------------------------------------
__device__ __forceinline__ unsigned ld_rlx(const unsigned* p) {
    return __hip_atomic_load(p, __ATOMIC_RELAXED, __HIP_MEMORY_SCOPE_AGENT);
}
__device__ __forceinline__ void wait1(const unsigned* p) {
    while (ld_rlx(p) == 0u) __builtin_amdgcn_s_sleep(1);
}
__device__ __forceinline__ void st_release(unsigned* p, unsigned v) {
    __hip_atomic_store(p, v, __ATOMIC_RELEASE, __HIP_MEMORY_SCOPE_AGENT);
}

// --------------------------------------------------------------------------
// init: clear flags + probe mask layout (int32 {0,1} has bytes 1..3 == 0).
__global__ void __launch_bounds__(BLK) k_init(const unsigned char* __restrict__ m,
                                              int* __restrict__ dflag,
                                              unsigned* __restrict__ cFlag,
                                              unsigned* __restrict__ gFlag) {
    int tid = threadIdx.x;
    for (int i = tid; i < NTILE; i += BLK) cFlag[i] = 0u;
    for (int i = tid; i < SL * NGRP; i += BLK) gFlag[i] = 0u;

    __shared__ unsigned sh[WAVES];
    unsigned v = 0;
    for (int i = tid; i < 65536; i += BLK)
        if (i & 3) v |= m[i];
    #pragma unroll
    for (int off = 32; off; off >>= 1) v |= __shfl_down(v, off);
    if ((tid & 63) == 0) sh[tid >> 6] = v;
    __syncthreads();
    if (tid == 0) {
        unsigned r = 0;
        #pragma unroll
        for (int w = 0; w < WAVES; ++w) r |= sh[w];
        *dflag = (r == 0) ? 1 : 0;   // 1 => int32 layout
    }
}

// --------------------------------------------------------------------------
#define ACC4(A_, R_)                         \
    do {                                     \
        A_.x = fmaf(GAMMA_F, A_.x, R_.x);    \
        A_.y = fmaf(GAMMA_F, A_.y, R_.y);    \
        A_.z = fmaf(GAMMA_F, A_.z, R_.z);    \
        A_.w = fmaf(GAMMA_F, A_.w, R_.w);    \
    } while (0)

#define AXPY4(X_, W_, S_)                    \
    do {                                     \
        X_.x = fmaf(W_, S_.x, X_.x);         \
        X_.y = fmaf(W_, S_.y, X_.y);         \
        X_.z = fmaf(W_, S_.z, X_.z);         \
        X_.w = fmaf(W_, S_.w, X_.w);         \
    } while (0)

#define COMP(MJ, GX, RX, VX, LX, ZX)                 \
    do {                                             \
        GX = fmaf(GAMMA_F, GX, RX);                  \
        float mm = (MJ);                             \
        float Gm = mm * GX, vm = mm * VX, lm = mm * LX; \
        a[0] += mm; a[1] += Gm;                      \
        a[2] = fmaf(Gm, GX, a[2]);                   \
        a[3] = fmaf(Gm, VX, a[3]);                   \
        a[4] += vm; a[5] = fmaf(vm, VX, a[5]);       \
        a[6] = fmaf(lm, GX, a[6]); a[7] += lm;       \
        a[8] = fmaf(mm, ZX, a[8]);                   \
        a[9] = fmaf(lm, VX, a[9]);                   \
    } while (0)

#define PIPE_LOAD(S_, I_)                                                    \
    do {                                                                     \
        int e_ = base + (I_) * B4;                                           \
        r##S_ = rw[e_]; v##S_ = vv[e_]; l##S_ = lq[e_]; z##S_ = en[e_];      \
        if constexpr (I32) { q##S_ = ((const int4*)mp)[e_]; }                \
        else { uchar4 u_ = ((const uchar4*)mp)[e_];                          \
               q##S_ = make_int4(u_.x, u_.y, u_.z, u_.w); }                  \
    } while (0)

#define PIPE_COMP(S_)                                                        \
    do {                                                                     \
        COMP((q##S_.x ? 1.f : 0.f), G.x, r##S_.x, v##S_.x, l##S_.x, z##S_.x);\
        COMP((q##S_.y ? 1.f : 0.f), G.y, r##S_.y, v##S_.y, l##S_.y, z##S_.y);\
        COMP((q##S_.z ? 1.f : 0.f), G.z, r##S_.z, v##S_.z, l##S_.z, z##S_.z);\
        COMP((q##S_.w ? 1.f : 0.f), G.w, r##S_.w, v##S_.w, l##S_.w, z##S_.w);\
    } while (0)

template<bool I32>
__device__ __forceinline__ void main_body(const float4* __restrict__ rw,
                                          const float4* __restrict__ vv,
                                          const float4* __restrict__ lq,
                                          const float4* __restrict__ en,
                                          const void*  __restrict__ mp,
                                          int base, float4& G, float a[10]) {
    float4 rA, vA, lA, zA, rB, vB, lB, zB;
    int4 qA, qB;
    PIPE_LOAD(A, L - 1);
    PIPE_LOAD(B, L - 2);
    #pragma unroll
    for (int i = L - 1; i >= 3; i -= 2) {
        PIPE_COMP(A);
        PIPE_LOAD(A, i - 2);
        PIPE_COMP(B);
        PIPE_LOAD(B, i - 3);
    }
    PIPE_COMP(A);   // row 1
    PIPE_COMP(B);   // row 0
}

// --------------------------------------------------------------------------
__global__ void __launch_bounds__(BLK) k_fused(
    const float4* __restrict__ rw, const float4* __restrict__ vv,
    const float4* __restrict__ lq, const float4* __restrict__ en,
    const void*  __restrict__ mp,  const int* __restrict__ dflag,
    float4* __restrict__ Sagg, float4* __restrict__ Gagg,
    unsigned* __restrict__ cFlag, unsigned* __restrict__ gFlag,
    double* __restrict__ partials)
{
    const int tid  = threadIdx.x;
    const int bid  = blockIdx.x;
    const int cIdx = bid >> 2;          // 0..255, 0 = LAST chunk
    const int c    = NC - 1 - cIdx;
    const int s    = bid & 3;
    const int b    = s * 256 + tid;     // float4 column
    const int base = c * L * B4 + b;

    // ---- phase 1: chunk-local discounted sum of rewards (Horner, pipelined)
    float4 Sloc = make_float4(0.f, 0.f, 0.f, 0.f);
    {
        float4 rA = rw[base + (L - 1) * B4];
        float4 rB = rw[base + (L - 2) * B4];
        #pragma unroll
        for (int i = L - 1; i >= 3; i -= 2) {
            ACC4(Sloc, rA); rA = rw[base + (i - 2) * B4];
            ACC4(Sloc, rB); rB = rw[base + (i - 3) * B4];
        }
        ACC4(Sloc, rA);
        ACC4(Sloc, rB);
    }
    const int tile = s * NC + c;
    Sagg[tile * 256 + tid] = Sloc;
    __syncthreads();                       // all payload stores drained
    if (tid == 0) st_release(&cFlag[tile], 1u);

    // ---- deterministic two-level walk: X = sum_{cc>c} G32^(cc-c-1) * S_cc
    const int g    = c >> 4;
    const int gend = (g << 4) + 15;        // last chunk of this group
    float4 X = make_float4(0.f, 0.f, 0.f, 0.f);
    float  w = 1.f;

    if (tid == 0 && gend > c) {
        for (int cc = c + 1; cc <= gend; ++cc) wait1(&cFlag[s * NC + cc]);
        (void)__hip_atomic_load(&cFlag[s * NC + gend], __ATOMIC_ACQUIRE,
                                __HIP_MEMORY_SCOPE_AGENT);
    }
    __syncthreads();
    for (int cc = c + 1; cc <= gend; ++cc) {
        float4 sv = Sagg[(s * NC + cc) * 256 + tid];
        AXPY4(X, w, sv);
        w *= G32;
    }

    if ((c & (GSZ - 1)) == 0) {            // group base: publish group aggregate
        float4 ga;
        ga.x = fmaf(G32, X.x, Sloc.x);
        ga.y = fmaf(G32, X.y, Sloc.y);
        ga.z = fmaf(G32, X.z, Sloc.z);
        ga.w = fmaf(G32, X.w, Sloc.w);
        Gagg[(s * NGRP + g) * 256 + tid] = ga;
        __syncthreads();
        if (tid == 0) st_release(&gFlag[s * NGRP + g], 1u);
    }

    if (tid == 0 && g + 1 < NGRP) {
        for (int gg = g + 1; gg < NGRP; ++gg) wait1(&gFlag[s * NGRP + gg]);
        (void)__hip_atomic_load(&gFlag[s * NGRP + NGRP - 1], __ATOMIC_ACQUIRE,
                                __HIP_MEMORY_SCOPE_AGENT);
    }
    __syncthreads();
    for (int gg = g + 1; gg < NGRP; ++gg) {
        float4 gv = Gagg[(s * NGRP + gg) * 256 + tid];
        AXPY4(X, w, gv);
        w *= G512;
    }

    // ---- phase 2: fused masked sums (rewards re-read is L2/L3-warm)
    float4 G = X;
    float a[10] = {0.f, 0.f, 0.f, 0.f, 0.f, 0.f, 0.f, 0.f, 0.f, 0.f};
    if (*dflag) main_body<true >(rw, vv, lq, en, mp, base, G, a);
    else        main_body<false>(rw, vv, lq, en, mp, base, G, a);

    // ---- deterministic block reduction in f64
    double d[10];
    #pragma unroll
    for (int k = 0; k < 10; ++k) d[k] = (double)a[k];
    #pragma unroll
    for (int k = 0; k < 10; ++k)
        #pragma unroll
        for (int off = 32; off; off >>= 1)
            d[k] += __shfl_down(d[k], off);

    __shared__ double sh[WAVES][10];
    int lane = tid & 63, wv = tid >> 6;
    if (lane == 0) {
        #pragma unroll
        for (int k = 0; k < 10; ++k) sh[wv][k] = d[k];
    }
    __syncthreads();
    if (tid == 0) {
        #pragma unroll
        for (int k = 0; k < 10; ++k) {
            double t = sh[0][k];
            #pragma unroll
            for (int ww = 1; ww < WAVES; ++ww) t += sh[ww][k];
            partials[(size_t)bid * 10 + k] = t;
        }
    }
}

// --------------------------------------------------------------------------
__global__ void __launch_bounds__(BLK) k_final(const double* __restrict__ partials,
                                               float* __restrict__ out) {
    double d[10];
    #pragma unroll
    for (int k = 0; k < 10; ++k) d[k] = 0.0;
    for (int i = threadIdx.x; i < NTILE; i += BLK) {
        #pragma unroll
        for (int k = 0; k < 10; ++k) d[k] += partials[(size_t)i * 10 + k];
    }
    #pragma unroll
    for (int k = 0; k < 10; ++k)
        #pragma unroll
        for (int off = 32; off; off >>= 1)
            d[k] += __shfl_down(d[k], off);

    __shared__ double sh[WAVES][10];
    int lane = threadIdx.x & 63, wv = threadIdx.x >> 6;
    if (lane == 0) {
        #pragma unroll
        for (int k = 0; k < 10; ++k) sh[wv][k] = d[k];
    }
    __syncthreads();
    if (threadIdx.x == 0) {
        double s[10];
        #pragma unroll
        for (int k = 0; k < 10; ++k) {
            double t = sh[0][k];
            #pragma unroll
            for (int ww = 1; ww < WAVES; ++ww) t += sh[ww][k];
            s[k] = t;
        }
        double n = s[0], SG = s[1], SG2 = s[2], SGv = s[3], Sv = s[4];
        double Sv2 = s[5], SlpG = s[6], Slp = s[7], Sent = s[8], Slpv = s[9];

        double mean = SG / n;
        double css  = SG2 - 2.0 * mean * SG + mean * mean * n;  // sum m*(G-mean)^2
        double var  = css / (n - 1.0);
        double sd   = sqrt(var);
        double sc   = 1.0 / (sd + 1e-8);

        double critic = sc * sc * css - 2.0 * sc * (SGv - mean * Sv) + Sv2;
        double actor  = -sc * (SlpG - mean * Slp) + Slpv - 0.01 * Sent;

        out[0] = (float)critic;
        out[1] = (float)actor;
    }
}

// --------------------------------------------------------------------------
extern "C" void kernel_launch(void* const* d_in, const int* in_sizes, int n_in,
                              void* d_out, int out_size, void* d_ws, size_t ws_size,
                              hipStream_t stream) {
    const float4* rw = (const float4*)d_in[0];
    const float4* vv = (const float4*)d_in[1];
    const float4* lq = (const float4*)d_in[2];
    const float4* en = (const float4*)d_in[3];
    const void*   mp = d_in[4];

    char* ws = (char*)d_ws;
    size_t off = 0;
    float4*   Sagg  = (float4*)(ws + off); off += (size_t)NTILE * 256 * 16;      // 4 MiB
    float4*   Gagg  = (float4*)(ws + off); off += (size_t)SL * NGRP * 256 * 16;  // 256 KiB
    double*   p1    = (double*)(ws + off); off += (size_t)NTILE * 10 * 8;        // 80 KiB
    unsigned* cFlag = (unsigned*)(ws + off); off += (size_t)NTILE * 4;
    unsigned* gFlag = (unsigned*)(ws + off); off += (size_t)SL * NGRP * 4;
    int*      dflag = (int*)(ws + off);

    k_init <<<1, BLK, 0, stream>>>((const unsigned char*)mp, dflag, cFlag, gFlag);
    k_fused<<<NTILE, BLK, 0, stream>>>(rw, vv, lq, en, mp, dflag,
                                       Sagg, Gagg, cFlag, gFlag, p1);
    k_final<<<1, BLK, 0, stream>>>(p1, (float*)d_out);
}